// Round 8
// baseline (176.087 us; speedup 1.0000x reference)
//
#include <hip/hip_runtime.h>
#include <hip/hip_bf16.h>

#define T_SEQ 512
#define NH 8
#define DEPTH 64
#define UNITS_ 512
#define SCALE2 2.8853900817779268f   // 2*log2(e)
#define LOG2E 1.4426950408889634f

typedef __attribute__((ext_vector_type(4))) short bshort4;
typedef __attribute__((ext_vector_type(8))) short short8;
typedef __attribute__((ext_vector_type(4))) float floatx4;
typedef __attribute__((ext_vector_type(2))) float floatx2;

// ---- bf16 helpers: split fp32 x = hi + lo (both bf16-representable) ----
static __device__ __forceinline__ short bfh(float x) {
    __hip_bfloat16 b(x);
    return *(short*)&b;
}
static __device__ __forceinline__ float bff(short s) {
    unsigned u = ((unsigned)(unsigned short)s) << 16;
    float f;
    __builtin_memcpy(&f, &u, 4);
    return f;
}
static __device__ __forceinline__ void split4(float4 x, bshort4& h, bshort4& l) {
    union { bshort4 v; short s[4]; } H, L;
    float xs[4] = {x.x, x.y, x.z, x.w};
    #pragma unroll
    for (int i = 0; i < 4; ++i) {
        short hh = bfh(xs[i]);
        H.s[i] = hh;
        L.s[i] = bfh(xs[i] - bff(hh));
    }
    h = H.v; l = L.v;
}
static __device__ __forceinline__ void split8(float4 x, float4 y, short8& h, short8& l) {
    union { short8 v; short s[8]; } H, L;
    float xs[8] = {x.x, x.y, x.z, x.w, y.x, y.y, y.z, y.w};
    #pragma unroll
    for (int i = 0; i < 8; ++i) {
        short hh = bfh(xs[i]);
        H.s[i] = hh;
        L.s[i] = bfh(xs[i] - bff(hh));
    }
    h = H.v; l = L.v;
}

// ---- packed fp32 helpers (target v_pk_fma_f32 / v_pk_mul_f32) ----
static __device__ __forceinline__ floatx2 pkfma(floatx2 a, floatx2 b, floatx2 c) {
    return __builtin_elementwise_fma(a, b, c);
}
static __device__ __forceinline__ floatx2 bc(float x) {
    floatx2 r = {x, x};
    return r;
}

// ======= fused QK projection (split-bf16 MFMA) + per-head transform =======
// Main loop UNCHANGED from verified R6 build. Only change: eq is written in
// t-pair-interleaved layout eq2[bh][(tp*64+e)*2 + (t&1)] so attn_v8 can use
// packed-fp32 (v_pk_fma_f32) over t-pairs with no cross-half shuffles.
__global__ __launch_bounds__(512) void qk_head_mfma(
    const float* __restrict__ query, const float* __restrict__ key,
    const float* __restrict__ Wq, const float* __restrict__ bq,
    const float* __restrict__ Wk, const float* __restrict__ bk,
    const float* __restrict__ Wq_h, const float* __restrict__ Wk_h,
    const float* __restrict__ bh,
    float* __restrict__ eq2, float* __restrict__ ekT,
    __hip_bfloat16* __restrict__ KhT)
{
    __shared__ __align__(16) short BUF[256 * 72];
    short (*Ah)[72] = (short(*)[72])BUF;
    short (*Al)[72] = (short(*)[72])(BUF + 64 * 72);
    short (*Wh)[72] = (short(*)[72])(BUF + 128 * 72);
    short (*Wl)[72] = (short(*)[72])(BUF + 192 * 72);
    float (*S1)[68] = (float(*)[68])BUF;
    float (*S2)[68] = (float(*)[68])(BUF + 8704);

    const int tid = threadIdx.x;
    const int which = blockIdx.z;            // 0 = Q path, 1 = K path
    const int h  = blockIdx.x;
    const int m0 = blockIdx.y * 64;          // row in [0,1024): b*512 + t
    const int n0 = h * 64;
    const int b  = m0 >> 9;
    const int t0 = m0 & 511;
    const int bh_i = b * NH + h;

    const float* In   = which ? key : query;
    const float* W    = which ? Wk  : Wq;
    const float* bias = which ? bk  : bq;
    const float* Wp   = (which ? Wk_h : Wq_h) + h * 4096;

    const int wv = tid >> 6;            // wave 0..7
    const int l  = tid & 63;
    const int ms = (wv & 3) * 16;       // m-strip
    const int ns = (wv >> 2) * 32;      // n-half
    const int fr = l & 15;              // fragment row/col index
    const int fq = l >> 4;              // k-slice quarter

    const int arow = tid >> 3;          // 0..63
    const int acol = (tid & 7) * 8;     // 0..56
    const int wn   = tid & 63;          // W: n 0..63 (lane-coalesced)
    const int wkb  = (tid >> 6) * 8;    // W: k base 0..56

    const int hwrow = tid >> 3;         // d 0..63
    const int hwcol = (tid & 7) * 8;    // e base
    float4 whA = *(const float4*)&Wp[hwrow * 64 + hwcol];
    float4 whB = *(const float4*)&Wp[hwrow * 64 + hwcol + 4];

    const float bb0 = bias[n0 + ns + fr];
    const float bb1 = bias[n0 + ns + 16 + fr];

    floatx4 acc0 = {0.f, 0.f, 0.f, 0.f};
    floatx4 acc1 = {0.f, 0.f, 0.f, 0.f};

    float4 a0 = *(const float4*)&In[(m0 + arow) * 512 + acol];
    float4 a1 = *(const float4*)&In[(m0 + arow) * 512 + acol + 4];
    float wr[8];
    #pragma unroll
    for (int i = 0; i < 8; ++i) wr[i] = W[(wkb + i) * 512 + n0 + wn];

    for (int k0 = 0; k0 < 512; k0 += 64) {
        __syncthreads();
        {   // convert + stage
            short8 h8, l8;
            split8(a0, a1, h8, l8);
            *(short8*)&Ah[arow][acol] = h8;
            *(short8*)&Al[arow][acol] = l8;
            union { short8 v; short s[8]; } WH, WL;
            #pragma unroll
            for (int i = 0; i < 8; ++i) {
                short hh = bfh(wr[i]);
                WH.s[i] = hh;
                WL.s[i] = bfh(wr[i] - bff(hh));
            }
            *(short8*)&Wh[wn][wkb] = WH.v;
            *(short8*)&Wl[wn][wkb] = WL.v;
        }
        __syncthreads();
        if (k0 + 64 < 512) {            // prefetch next k-tile under the MFMAs
            a0 = *(const float4*)&In[(m0 + arow) * 512 + k0 + 64 + acol];
            a1 = *(const float4*)&In[(m0 + arow) * 512 + k0 + 64 + acol + 4];
            #pragma unroll
            for (int i = 0; i < 8; ++i)
                wr[i] = W[(k0 + 64 + wkb + i) * 512 + n0 + wn];
        }
        #pragma unroll
        for (int kc = 0; kc < 2; ++kc) {
            const int ko = kc * 32 + fq * 8;
            short8 ah  = *(const short8*)&Ah[ms + fr][ko];
            short8 al  = *(const short8*)&Al[ms + fr][ko];
            short8 w0h = *(const short8*)&Wh[ns + fr][ko];
            short8 w0l = *(const short8*)&Wl[ns + fr][ko];
            short8 w1h = *(const short8*)&Wh[ns + 16 + fr][ko];
            short8 w1l = *(const short8*)&Wl[ns + 16 + fr][ko];
            acc0 = __builtin_amdgcn_mfma_f32_16x16x32_bf16(ah, w0h, acc0, 0, 0, 0);
            acc1 = __builtin_amdgcn_mfma_f32_16x16x32_bf16(ah, w1h, acc1, 0, 0, 0);
            acc0 = __builtin_amdgcn_mfma_f32_16x16x32_bf16(ah, w0l, acc0, 0, 0, 0);
            acc1 = __builtin_amdgcn_mfma_f32_16x16x32_bf16(ah, w1l, acc1, 0, 0, 0);
            acc0 = __builtin_amdgcn_mfma_f32_16x16x32_bf16(al, w0h, acc0, 0, 0, 0);
            acc1 = __builtin_amdgcn_mfma_f32_16x16x32_bf16(al, w1h, acc1, 0, 0, 0);
        }
    }

    // ---- stage 2: per-head 64x64 transform (fp32 VALU) ----
    __syncthreads();
    #pragma unroll
    for (int r = 0; r < 4; ++r) {
        S1[ns + fr][ms + fq * 4 + r]      = acc0[r] + bb0;
        S1[ns + 16 + fr][ms + fq * 4 + r] = acc1[r] + bb1;
    }
    *(float4*)&S2[hwrow][hwcol]     = whA;
    *(float4*)&S2[hwrow][hwcol + 4] = whB;
    __syncthreads();

    const int ti = tid >> 4;            // 0..31 -> rows 2ti, 2ti+1 (a t-pair!)
    const int tj = tid & 15;            // cols 4tj..4tj+3
    float4 qa0 = make_float4(0.f, 0.f, 0.f, 0.f);
    float4 qa1 = make_float4(0.f, 0.f, 0.f, 0.f);
    #pragma unroll 8
    for (int d = 0; d < 64; ++d) {
        float2 a2 = *(const float2*)&S1[d][2 * ti];
        float4 b4 = *(const float4*)&S2[d][4 * tj];
        qa0.x = fmaf(a2.x, b4.x, qa0.x);
        qa0.y = fmaf(a2.x, b4.y, qa0.y);
        qa0.z = fmaf(a2.x, b4.z, qa0.z);
        qa0.w = fmaf(a2.x, b4.w, qa0.w);
        qa1.x = fmaf(a2.y, b4.x, qa1.x);
        qa1.y = fmaf(a2.y, b4.y, qa1.y);
        qa1.z = fmaf(a2.y, b4.z, qa1.z);
        qa1.w = fmaf(a2.y, b4.w, qa1.w);
    }

    if (which == 0) {
        // t-pair-interleaved eq2: addr(tp_g, e, p) = tp_g*128 + 2e + p.
        // This thread: tp_g = t0/2 + ti (rows 2ti=p0, 2ti+1=p1), e = 4tj..4tj+3.
        float* outp = eq2 + (size_t)bh_i * 32768 + ((size_t)(t0 >> 1) + ti) * 128 + 8 * tj;
        float e00 = __builtin_amdgcn_exp2f(SCALE2 * qa0.x);
        float e10 = __builtin_amdgcn_exp2f(SCALE2 * qa1.x);
        float e01 = __builtin_amdgcn_exp2f(SCALE2 * qa0.y);
        float e11 = __builtin_amdgcn_exp2f(SCALE2 * qa1.y);
        float e02 = __builtin_amdgcn_exp2f(SCALE2 * qa0.z);
        float e12 = __builtin_amdgcn_exp2f(SCALE2 * qa1.z);
        float e03 = __builtin_amdgcn_exp2f(SCALE2 * qa0.w);
        float e13 = __builtin_amdgcn_exp2f(SCALE2 * qa1.w);
        *(float4*)&outp[0] = make_float4(e00, e10, e01, e11);
        *(float4*)&outp[4] = make_float4(e02, e12, e03, e13);
        return;
    }

    // which == 1: ekT (transposed, exp2'd, +b_h) and KhT (bf16 of C^T)
    float4 bhv = *(const float4*)&bh[h * 64 + 4 * tj];
    __syncthreads();
    S2[4 * tj + 0][2 * ti + 0] = __builtin_amdgcn_exp2f(SCALE2 * (qa0.x + bhv.x));
    S2[4 * tj + 0][2 * ti + 1] = __builtin_amdgcn_exp2f(SCALE2 * (qa1.x + bhv.x));
    S2[4 * tj + 1][2 * ti + 0] = __builtin_amdgcn_exp2f(SCALE2 * (qa0.y + bhv.y));
    S2[4 * tj + 1][2 * ti + 1] = __builtin_amdgcn_exp2f(SCALE2 * (qa1.y + bhv.y));
    S2[4 * tj + 2][2 * ti + 0] = __builtin_amdgcn_exp2f(SCALE2 * (qa0.z + bhv.z));
    S2[4 * tj + 2][2 * ti + 1] = __builtin_amdgcn_exp2f(SCALE2 * (qa1.z + bhv.z));
    S2[4 * tj + 3][2 * ti + 0] = __builtin_amdgcn_exp2f(SCALE2 * (qa0.w + bhv.w));
    S2[4 * tj + 3][2 * ti + 1] = __builtin_amdgcn_exp2f(SCALE2 * (qa1.w + bhv.w));
    __syncthreads();

    const int dd = tid >> 3;            // e (or d) 0..63
    const int sc = (tid & 7) * 8;       // s chunk
    float* ekp = ekT + ((size_t)bh_i * 64 + dd) * 512 + t0 + sc;
    *(float4*)&ekp[0] = *(float4*)&S2[dd][sc];
    *(float4*)&ekp[4] = *(float4*)&S2[dd][sc + 4];

    __hip_bfloat16* kp = KhT + ((size_t)bh_i * 64 + dd) * 512 + t0 + sc;
    union { short8 v; short s[8]; } pk;
    #pragma unroll
    for (int i = 0; i < 8; ++i) pk.s[i] = bfh(S1[dd][sc + i]);
    *(short8*)kp = pk.v;
}

// ============ additive-attention core v8: packed-fp32 over t-pairs ============
// v7 was fp32-VALU-issue-bound (~3.8K scalar ops/thread). v8 packs the rational
// tree over t-pairs into float2 ext-vectors -> v_pk_fma_f32/v_pk_mul_f32
// (2 fp32 per instr, gfx90a+). ek/va are t-invariant (broadcast into both
// halves); eq comes pre-interleaved from qk (eq2 layout) so no shuffles.
// Per-t arithmetic order identical to v7 -> bit-identical results.
__global__ __launch_bounds__(512, 4) void attn_v8(
    const float* __restrict__ eq2, const float* __restrict__ ekT,
    const __hip_bfloat16* __restrict__ KhT, const float* __restrict__ va_h,
    float* __restrict__ merged)
{
    __shared__ __hip_bfloat16 pA[16][520];   // p in MFMA-A layout source, bf16
    __shared__ float wsum[16][8];

    const int tid = threadIdx.x;
    const int w = tid >> 6;
    const int l = tid & 63;
    const int bid = blockIdx.x;
    const int swz = (bid & 7) * 64 + (bid >> 3);   // bijective: 512 % 8 == 0
    const int t0 = (swz & 31) * 16;
    const int bh_i = swz >> 5;          // 0..15 = b*8 + h
    const int h = bh_i & 7;
    const int b = bh_i >> 3;

    // eq2 block base: t-pairs tp = t0/2 .. t0/2+7, layout tp*128 + 2e + p
    const float* eqb_p = eq2 + (size_t)bh_i * 32768 + (size_t)(t0 >> 1) * 128;
    const float* ekT_p = ekT + (size_t)bh_i * 64 * 512 + tid;   // this thread's s
    const float* va_p = va_h + h * 64;

    floatx2 accp[8];
    #pragma unroll
    for (int tp = 0; tp < 8; ++tp) accp[tp] = bc(0.f);

    const floatx2 one2 = {1.0f, 1.0f};

    // e processed in 4 chunks of 16, ek double-buffered in NAMED arrays
    float ekA[16], ekB[16];
    #pragma unroll
    for (int j = 0; j < 16; ++j) ekA[j] = ekT_p[j * 512];

#define SCORE_CHUNK(EKREG, E0)                                                  \
    {                                                                           \
        _Pragma("unroll")                                                       \
        for (int tp = 0; tp < 8; ++tp) {                                        \
            floatx2 a = accp[tp];                                               \
            const float* qp = eqb_p + tp * 128 + 2 * (E0);                      \
            _Pragma("unroll")                                                   \
            for (int g = 0; g < 4; ++g) {                                       \
                float4 L0 = *(const float4*)&qp[8 * g];                         \
                float4 L1 = *(const float4*)&qp[8 * g + 4];                     \
                floatx2 q0 = {L0.x, L0.y}, q1 = {L0.z, L0.w};                   \
                floatx2 q2 = {L1.x, L1.y}, q3 = {L1.z, L1.w};                   \
                floatx2 u0 = pkfma(q0, bc(EKREG[4 * g + 0]), one2);             \
                floatx2 u1 = pkfma(q1, bc(EKREG[4 * g + 1]), one2);             \
                floatx2 u2 = pkfma(q2, bc(EKREG[4 * g + 2]), one2);             \
                floatx2 u3 = pkfma(q3, bc(EKREG[4 * g + 3]), one2);             \
                floatx2 d01 = u0 * u1;                                          \
                floatx2 n01 = pkfma(bc(va_p[(E0) + 4 * g + 0]), u1,             \
                                    bc(va_p[(E0) + 4 * g + 1]) * u0);           \
                floatx2 d23 = u2 * u3;                                          \
                floatx2 n23 = pkfma(bc(va_p[(E0) + 4 * g + 2]), u3,             \
                                    bc(va_p[(E0) + 4 * g + 3]) * u2);           \
                floatx2 D = d01 * d23;                                          \
                floatx2 N = pkfma(n01, d23, n23 * d01);                         \
                floatx2 r = {__builtin_amdgcn_rcpf(D.x),                        \
                             __builtin_amdgcn_rcpf(D.y)};                       \
                a = pkfma(N, r, a);                                             \
            }                                                                   \
            accp[tp] = a;                                                       \
        }                                                                       \
    }

    #pragma unroll
    for (int j = 0; j < 16; ++j) ekB[j] = ekT_p[(16 + j) * 512];
    SCORE_CHUNK(ekA, 0)
    #pragma unroll
    for (int j = 0; j < 16; ++j) ekA[j] = ekT_p[(32 + j) * 512];
    SCORE_CHUNK(ekB, 16)
    #pragma unroll
    for (int j = 0; j < 16; ++j) ekB[j] = ekT_p[(48 + j) * 512];
    SCORE_CHUNK(ekA, 32)
    SCORE_CHUNK(ekB, 48)
#undef SCORE_CHUNK

    // unpack t-pairs, exp, per-t sum across 512 threads
    float ev[16];
    #pragma unroll
    for (int tp = 0; tp < 8; ++tp) {
        ev[2 * tp + 0] = __builtin_amdgcn_exp2f(-SCALE2 * accp[tp].x);
        ev[2 * tp + 1] = __builtin_amdgcn_exp2f(-SCALE2 * accp[tp].y);
    }
    #pragma unroll
    for (int t = 0; t < 16; ++t) {
        float s = ev[t];
        #pragma unroll
        for (int off = 32; off > 0; off >>= 1) s += __shfl_xor(s, off, 64);
        if (l == 0) wsum[t][w] = s;
    }
    __syncthreads();
    #pragma unroll
    for (int t = 0; t < 16; ++t) {
        float4 s0 = *(float4*)&wsum[t][0];
        float4 s1 = *(float4*)&wsum[t][4];
        float inv = 1.0f / (((s0.x + s0.y) + (s0.z + s0.w)) + ((s1.x + s1.y) + (s1.z + s1.w)));
        pA[t][tid] = __hip_bfloat16(ev[t] * inv);   // normalized p, bf16
    }
    __syncthreads();

    // P (16x512) @ K (512x64): 4 waves, wave w owns d-range [16w,16w+16)
    if (w < 4) {
        const __hip_bfloat16* kp = KhT + (size_t)bh_i * 64 * 512
                                   + ((size_t)(w * 16 + (l & 15))) * 512 + (l >> 4) * 8;
        const __hip_bfloat16* ap = &pA[l & 15][(l >> 4) * 8];
        floatx4 oacc = {0.f, 0.f, 0.f, 0.f};
        #pragma unroll
        for (int kt = 0; kt < 16; ++kt) {
            short8 af = *(const short8*)(ap + kt * 32);
            short8 bf = *(const short8*)(kp + kt * 32);
            oacc = __builtin_amdgcn_mfma_f32_16x16x32_bf16(af, bf, oacc, 0, 0, 0);
        }
        const int row = (l >> 4) * 4;        // t_local base
        const int col = w * 16 + (l & 15);   // d
        float* mp = merged + ((size_t)(b * 512 + t0 + row)) * 512 + h * 64 + col;
        #pragma unroll
        for (int r = 0; r < 4; ++r) mp[r * 512] = oacc[r];
    }
}

// ======= output projection (split-bf16 MFMA): C = A@Wo + bo =======
// UNCHANGED from verified R6 build.
__global__ __launch_bounds__(512) void gemm_out_mfma(
    const float* __restrict__ A, const float* __restrict__ W,
    const float* __restrict__ bias, float* __restrict__ C)
{
    __shared__ __align__(16) short BUF[192 * 72];
    short (*Ah)[72] = (short(*)[72])BUF;
    short (*Al)[72] = (short(*)[72])(BUF + 32 * 72);
    short (*Wh)[72] = (short(*)[72])(BUF + 64 * 72);
    short (*Wl)[72] = (short(*)[72])(BUF + 128 * 72);

    const int tid = threadIdx.x;
    const int n0 = blockIdx.x * 64;
    const int m0 = blockIdx.y * 32;
    const int wv = tid >> 6;
    const int l  = tid & 63;
    const int ms = (wv & 1) * 16;
    const int ns = (wv >> 1) * 16;
    const int fr = l & 15;
    const int fq = l >> 4;

    const int arow = tid >> 4;          // 0..31
    const int acol = (tid & 15) * 4;    // 0..60
    const int wn   = tid & 63;
    const int wkb  = (tid >> 6) * 8;

    const float bb = bias[n0 + ns + fr];
    floatx4 acc = {0.f, 0.f, 0.f, 0.f};

    float4 a0 = *(const float4*)&A[(m0 + arow) * 512 + acol];
    float wr[8];
    #pragma unroll
    for (int i = 0; i < 8; ++i) wr[i] = W[(wkb + i) * 512 + n0 + wn];

    for (int k0 = 0; k0 < 512; k0 += 64) {
        __syncthreads();
        {
            bshort4 h4, l4;
            split4(a0, h4, l4);
            *(bshort4*)&Ah[arow][acol] = h4;
            *(bshort4*)&Al[arow][acol] = l4;
            union { short8 v; short s[8]; } WH, WL;
            #pragma unroll
            for (int i = 0; i < 8; ++i) {
                short hh = bfh(wr[i]);
                WH.s[i] = hh;
                WL.s[i] = bfh(wr[i] - bff(hh));
            }
            *(short8*)&Wh[wn][wkb] = WH.v;
            *(short8*)&Wl[wn][wkb] = WL.v;
        }
        __syncthreads();
        if (k0 + 64 < 512) {
            a0 = *(const float4*)&A[(m0 + arow) * 512 + k0 + 64 + acol];
            #pragma unroll
            for (int i = 0; i < 8; ++i)
                wr[i] = W[(k0 + 64 + wkb + i) * 512 + n0 + wn];
        }
        #pragma unroll
        for (int kc = 0; kc < 2; ++kc) {
            const int ko = kc * 32 + fq * 8;
            short8 ah = *(const short8*)&Ah[ms + fr][ko];
            short8 al = *(const short8*)&Al[ms + fr][ko];
            short8 wh = *(const short8*)&Wh[ns + fr][ko];
            short8 wl = *(const short8*)&Wl[ns + fr][ko];
            acc = __builtin_amdgcn_mfma_f32_16x16x32_bf16(ah, wh, acc, 0, 0, 0);
            acc = __builtin_amdgcn_mfma_f32_16x16x32_bf16(ah, wl, acc, 0, 0, 0);
            acc = __builtin_amdgcn_mfma_f32_16x16x32_bf16(al, wh, acc, 0, 0, 0);
        }
    }

    const int mrow = m0 + ms + fq * 4;
    const int ncol = n0 + ns + fr;
    #pragma unroll
    for (int r = 0; r < 4; ++r)
        C[(size_t)(mrow + r) * 512 + ncol] = acc[r] + bb;
}

extern "C" void kernel_launch(void* const* d_in, const int* in_sizes, int n_in,
                              void* d_out, int out_size, void* d_ws, size_t ws_size,
                              hipStream_t stream) {
    (void)in_sizes; (void)n_in; (void)out_size; (void)ws_size;
    const float* query = (const float*)d_in[0];
    const float* key   = (const float*)d_in[1];
    // d_in[2] (value), d_in[7] (Wv), d_in[8] (bv): dead in the reference
    const float* Wq   = (const float*)d_in[3];
    const float* bq   = (const float*)d_in[4];
    const float* Wk   = (const float*)d_in[5];
    const float* bk   = (const float*)d_in[6];
    const float* Wq_h = (const float*)d_in[9];
    const float* Wk_h = (const float*)d_in[10];
    const float* va_h = (const float*)d_in[11];
    const float* b_h  = (const float*)d_in[12];
    const float* Wo   = (const float*)d_in[13];
    const float* bo   = (const float*)d_in[14];

    float* out = (float*)d_out;
    float* ws = (float*)d_ws;
    const int SZ = 1024 * 512;        // 524288 floats
    float* eq2b    = ws;
    float* ekTb    = eq2b + SZ;
    float* mergedb = ekTb + SZ;
    __hip_bfloat16* KhTb = (__hip_bfloat16*)(mergedb + SZ);   // 524288 bf16

    // fused: {Q,K} = In@W+b (split-bf16 MFMA), per-head transform -> eq2/ekT/KhT
    qk_head_mfma<<<dim3(8, 16, 2), 512, 0, stream>>>(query, key, Wq, bq, Wk, bk,
                                                     Wq_h, Wk_h, b_h,
                                                     eq2b, ekTb, KhTb);
    // scores (packed-fp32 t-pairs) -> softmax -> P@K (MFMA); XCD-swizzled
    attn_v8<<<dim3(512, 1, 1), 512, 0, stream>>>(eq2b, ekTb, KhTb, va_h, mergedb);
    // out = merged@Wo + bo (split-bf16 MFMA, 256 blocks)
    gemm_out_mfma<<<dim3(8, 32, 1), 512, 0, stream>>>(mergedb, Wo, bo, out);
}

// Round 10
// 158.768 us; speedup vs baseline: 1.1091x; 1.1091x over previous
//
#include <hip/hip_runtime.h>
#include <hip/hip_bf16.h>

#define T_SEQ 512
#define NH 8
#define DEPTH 64
#define UNITS_ 512
#define SCALE2 2.8853900817779268f   // 2*log2(e)
#define LOG2E 1.4426950408889634f

typedef __attribute__((ext_vector_type(4))) short bshort4;
typedef __attribute__((ext_vector_type(8))) short short8;
typedef __attribute__((ext_vector_type(4))) float floatx4;

// ---- bf16 helpers: split fp32 x = hi + lo (both bf16-representable) ----
static __device__ __forceinline__ short bfh(float x) {
    __hip_bfloat16 b(x);
    return *(short*)&b;
}
static __device__ __forceinline__ float bff(short s) {
    unsigned u = ((unsigned)(unsigned short)s) << 16;
    float f;
    __builtin_memcpy(&f, &u, 4);
    return f;
}
static __device__ __forceinline__ void split4(float4 x, bshort4& h, bshort4& l) {
    union { bshort4 v; short s[4]; } H, L;
    float xs[4] = {x.x, x.y, x.z, x.w};
    #pragma unroll
    for (int i = 0; i < 4; ++i) {
        short hh = bfh(xs[i]);
        H.s[i] = hh;
        L.s[i] = bfh(xs[i] - bff(hh));
    }
    h = H.v; l = L.v;
}

// ======= fused QK projection (split-bf16 MFMA) + per-head transform =======
// v2: 32-row m-tiles -> grid (8,32,2) = 512 blocks (2 blocks/CU, 4 waves/SIMD).
// Same verified 3-pass split-bf16 MFMA fragment math; each wave owns one
// 16x16 output tile (ms = (wv&1)*16, ns16 = (wv>>1)*16).
__global__ __launch_bounds__(512) void qk_head_mfma(
    const float* __restrict__ query, const float* __restrict__ key,
    const float* __restrict__ Wq, const float* __restrict__ bq,
    const float* __restrict__ Wk, const float* __restrict__ bk,
    const float* __restrict__ Wq_h, const float* __restrict__ Wk_h,
    const float* __restrict__ bh,
    float* __restrict__ eq, float* __restrict__ ekT,
    __hip_bfloat16* __restrict__ KhT)
{
    // stage1: Ah/Al bf16[32][72], Wh/Wl bf16[64][72]  (27648 B)
    // stage2 (aliased): S1 = C^T fp32[64][36] (9216 B), S2 fp32[64][68] (17408 B)
    __shared__ __align__(16) short BUF[192 * 72];
    short (*Ah)[72] = (short(*)[72])BUF;
    short (*Al)[72] = (short(*)[72])(BUF + 32 * 72);
    short (*Wh)[72] = (short(*)[72])(BUF + 64 * 72);
    short (*Wl)[72] = (short(*)[72])(BUF + 128 * 72);
    float (*S1)[36] = (float(*)[36])BUF;                 // C^T [n64][m32]
    float (*S2)[68] = (float(*)[68])(BUF + 4608);        // byte offset 9216

    const int tid = threadIdx.x;
    const int which = blockIdx.z;            // 0 = Q path, 1 = K path
    const int h  = blockIdx.x;
    const int m0 = blockIdx.y * 32;          // row in [0,1024): b*512 + t
    const int n0 = h * 64;
    const int b  = m0 >> 9;
    const int t0 = m0 & 511;
    const int bh_i = b * NH + h;

    const float* In   = which ? key : query;
    const float* W    = which ? Wk  : Wq;
    const float* bias = which ? bk  : bq;
    const float* Wp   = (which ? Wk_h : Wq_h) + h * 4096;

    const int wv = tid >> 6;            // wave 0..7
    const int l  = tid & 63;
    const int ms = (wv & 1) * 16;       // m-strip
    const int ns16 = (wv >> 1) * 16;    // n-tile (4 tiles of 16)
    const int fr = l & 15;              // fragment row/col index
    const int fq = l >> 4;              // k-slice quarter

    // staging indices
    const int arow = tid >> 4;          // 0..31
    const int acol = (tid & 15) * 4;    // 0..60
    const int wn   = tid & 63;          // W: n 0..63 (lane-coalesced)
    const int wkb  = (tid >> 6) * 8;    // W: k base 0..56

    // per-head weight tile prefetch (held in regs through stage 1)
    const int hwrow = tid >> 3;         // d 0..63
    const int hwcol = (tid & 7) * 8;    // e base
    float4 whA = *(const float4*)&Wp[hwrow * 64 + hwcol];
    float4 whB = *(const float4*)&Wp[hwrow * 64 + hwcol + 4];

    const float bbn = bias[n0 + ns16 + fr];

    floatx4 acc = {0.f, 0.f, 0.f, 0.f};

    // prefetch k-tile 0
    float4 a0 = *(const float4*)&In[(m0 + arow) * 512 + acol];
    float wr[8];
    #pragma unroll
    for (int i = 0; i < 8; ++i) wr[i] = W[(wkb + i) * 512 + n0 + wn];

    for (int k0 = 0; k0 < 512; k0 += 64) {
        __syncthreads();
        {   // convert + stage
            bshort4 h4, l4;
            split4(a0, h4, l4);
            *(bshort4*)&Ah[arow][acol] = h4;
            *(bshort4*)&Al[arow][acol] = l4;
            union { short8 v; short s[8]; } WH, WL;
            #pragma unroll
            for (int i = 0; i < 8; ++i) {
                short hh = bfh(wr[i]);
                WH.s[i] = hh;
                WL.s[i] = bfh(wr[i] - bff(hh));
            }
            *(short8*)&Wh[wn][wkb] = WH.v;
            *(short8*)&Wl[wn][wkb] = WL.v;
        }
        __syncthreads();
        if (k0 + 64 < 512) {            // prefetch next k-tile under the MFMAs
            a0 = *(const float4*)&In[(m0 + arow) * 512 + k0 + 64 + acol];
            #pragma unroll
            for (int i = 0; i < 8; ++i)
                wr[i] = W[(k0 + 64 + wkb + i) * 512 + n0 + wn];
        }
        #pragma unroll
        for (int kc = 0; kc < 2; ++kc) {
            const int ko = kc * 32 + fq * 8;
            short8 ah = *(const short8*)&Ah[ms + fr][ko];
            short8 al = *(const short8*)&Al[ms + fr][ko];
            short8 wh = *(const short8*)&Wh[ns16 + fr][ko];
            short8 wl = *(const short8*)&Wl[ns16 + fr][ko];
            acc = __builtin_amdgcn_mfma_f32_16x16x32_bf16(ah, wh, acc, 0, 0, 0);
            acc = __builtin_amdgcn_mfma_f32_16x16x32_bf16(ah, wl, acc, 0, 0, 0);
            acc = __builtin_amdgcn_mfma_f32_16x16x32_bf16(al, wh, acc, 0, 0, 0);
        }
    }

    // ---- stage 2: per-head 32x64 @ 64x64 transform (fp32 VALU) ----
    __syncthreads();   // all MFMA LDS reads done; BUF repurposed
    #pragma unroll
    for (int r = 0; r < 4; ++r)
        S1[ns16 + fr][ms + fq * 4 + r] = acc[r] + bbn;    // C^T [n][m]
    *(float4*)&S2[hwrow][hwcol]     = whA;                // Wh_head [d][e]
    *(float4*)&S2[hwrow][hwcol + 4] = whB;
    __syncthreads();

    const int ti = tid >> 4;            // row t 0..31 (16-lane groups share row)
    const int tj = tid & 15;            // cols 4tj..4tj+3
    float4 qa = make_float4(0.f, 0.f, 0.f, 0.f);
    #pragma unroll 16
    for (int d = 0; d < 64; ++d) {
        float a = S1[d][ti];            // broadcast within 16-lane group
        float4 b4 = *(const float4*)&S2[d][4 * tj];
        qa.x = fmaf(a, b4.x, qa.x);
        qa.y = fmaf(a, b4.y, qa.y);
        qa.z = fmaf(a, b4.z, qa.z);
        qa.w = fmaf(a, b4.w, qa.w);
    }

    if (which == 0) {
        float* outp = eq + ((size_t)bh_i * 512 + t0 + ti) * 64 + 4 * tj;
        float4 o;
        o.x = __builtin_amdgcn_exp2f(SCALE2 * qa.x);
        o.y = __builtin_amdgcn_exp2f(SCALE2 * qa.y);
        o.z = __builtin_amdgcn_exp2f(SCALE2 * qa.z);
        o.w = __builtin_amdgcn_exp2f(SCALE2 * qa.w);
        *(float4*)outp = o;
        return;
    }

    // which == 1: ekT (transposed, exp2'd, +b_h) and KhT (bf16 of C^T)
    float4 bhv = *(const float4*)&bh[h * 64 + 4 * tj];
    __syncthreads();   // all threads done reading S2 as per-head weights
    S2[4 * tj + 0][ti] = __builtin_amdgcn_exp2f(SCALE2 * (qa.x + bhv.x));
    S2[4 * tj + 1][ti] = __builtin_amdgcn_exp2f(SCALE2 * (qa.y + bhv.y));
    S2[4 * tj + 2][ti] = __builtin_amdgcn_exp2f(SCALE2 * (qa.z + bhv.z));
    S2[4 * tj + 3][ti] = __builtin_amdgcn_exp2f(SCALE2 * (qa.w + bhv.w));
    __syncthreads();

    const int dd = tid >> 3;            // e (or d) 0..63
    const int sc = (tid & 7) * 4;       // s chunk 0..28
    float* ekp = ekT + ((size_t)bh_i * 64 + dd) * 512 + t0 + sc;
    *(float4*)ekp = *(float4*)&S2[dd][sc];

    __hip_bfloat16* kp = KhT + ((size_t)bh_i * 64 + dd) * 512 + t0 + sc;
    union { bshort4 v; short s[4]; } pk;
    #pragma unroll
    for (int i = 0; i < 4; ++i) pk.s[i] = bfh(S1[dd][sc + i]);
    *(bshort4*)kp = pk.v;
}

// ============ additive-attention core v7 (VERBATIM from verified R7, 58 us) ============
__global__ __launch_bounds__(512, 4) void attn_v7(
    const float* __restrict__ eq, const float* __restrict__ ekT,
    const __hip_bfloat16* __restrict__ KhT, const float* __restrict__ va_h,
    float* __restrict__ merged)
{
    __shared__ __hip_bfloat16 pA[16][520];   // p in MFMA-A layout source, bf16
    __shared__ float wsum[16][8];

    const int tid = threadIdx.x;
    const int w = tid >> 6;
    const int l = tid & 63;
    const int bid = blockIdx.x;
    const int swz = (bid & 7) * 64 + (bid >> 3);   // bijective: 512 % 8 == 0
    const int t0 = (swz & 31) * 16;
    const int bh_i = swz >> 5;          // 0..15 = b*8 + h
    const int h = bh_i & 7;
    const int b = bh_i >> 3;

    const float* eq_p = eq + ((size_t)bh_i * 512 + t0) * 64;
    const float* ekT_p = ekT + (size_t)bh_i * 64 * 512 + tid;   // this thread's s
    const float* va_p = va_h + h * 64;

    float acc[16];
    #pragma unroll
    for (int t = 0; t < 16; ++t) acc[t] = 0.f;

    // process e in 4 chunks of 16, double-buffered in NAMED arrays (rule #20)
    float ekA[16], ekB[16];
    #pragma unroll
    for (int j = 0; j < 16; ++j) ekA[j] = ekT_p[j * 512];

#define SCORE_CHUNK(EKREG, E0)                                                  \
    {                                                                           \
        _Pragma("unroll")                                                       \
        for (int t = 0; t < 16; ++t) {                                          \
            float a = acc[t];                                                   \
            _Pragma("unroll")                                                   \
            for (int g = 0; g < 4; ++g) {                                       \
                float4 q4 = *(const float4*)&eq_p[t * 64 + (E0) + g * 4];       \
                float4 v4 = *(const float4*)&va_p[(E0) + g * 4];                \
                float u0 = fmaf(q4.x, EKREG[g * 4 + 0], 1.0f);                  \
                float u1 = fmaf(q4.y, EKREG[g * 4 + 1], 1.0f);                  \
                float u2 = fmaf(q4.z, EKREG[g * 4 + 2], 1.0f);                  \
                float u3 = fmaf(q4.w, EKREG[g * 4 + 3], 1.0f);                  \
                float d01 = u0 * u1;                                            \
                float n01 = fmaf(v4.x, u1, v4.y * u0);                          \
                float d23 = u2 * u3;                                            \
                float n23 = fmaf(v4.z, u3, v4.w * u2);                          \
                float D = d01 * d23;                                            \
                float N = fmaf(n01, d23, n23 * d01);                            \
                a = fmaf(N, __builtin_amdgcn_rcpf(D), a);                       \
            }                                                                   \
            acc[t] = a;                                                         \
        }                                                                       \
    }

    #pragma unroll
    for (int j = 0; j < 16; ++j) ekB[j] = ekT_p[(16 + j) * 512];
    SCORE_CHUNK(ekA, 0)
    #pragma unroll
    for (int j = 0; j < 16; ++j) ekA[j] = ekT_p[(32 + j) * 512];
    SCORE_CHUNK(ekB, 16)
    #pragma unroll
    for (int j = 0; j < 16; ++j) ekB[j] = ekT_p[(48 + j) * 512];
    SCORE_CHUNK(ekA, 32)
    SCORE_CHUNK(ekB, 48)
#undef SCORE_CHUNK

    // exp (no max-subtract; |score| bounded ~5) + per-t sum across 512 threads
    float ev[16];
    #pragma unroll
    for (int t = 0; t < 16; ++t) {
        float s = __builtin_amdgcn_exp2f(-SCALE2 * acc[t]);   // exp(-2*S_t)
        ev[t] = s;
        #pragma unroll
        for (int off = 32; off > 0; off >>= 1) s += __shfl_xor(s, off, 64);
        if (l == 0) wsum[t][w] = s;
    }
    __syncthreads();
    #pragma unroll
    for (int t = 0; t < 16; ++t) {
        float4 s0 = *(float4*)&wsum[t][0];
        float4 s1 = *(float4*)&wsum[t][4];
        float inv = 1.0f / (((s0.x + s0.y) + (s0.z + s0.w)) + ((s1.x + s1.y) + (s1.z + s1.w)));
        pA[t][tid] = __hip_bfloat16(ev[t] * inv);   // normalized p, bf16
    }
    __syncthreads();

    // P (16x512) @ K (512x64): 4 waves, wave w owns d-range [16w,16w+16)
    if (w < 4) {
        const __hip_bfloat16* kp = KhT + (size_t)bh_i * 64 * 512
                                   + ((size_t)(w * 16 + (l & 15))) * 512 + (l >> 4) * 8;
        const __hip_bfloat16* ap = &pA[l & 15][(l >> 4) * 8];
        floatx4 oacc = {0.f, 0.f, 0.f, 0.f};
        #pragma unroll
        for (int kt = 0; kt < 16; ++kt) {
            short8 af = *(const short8*)(ap + kt * 32);
            short8 bf = *(const short8*)(kp + kt * 32);
            oacc = __builtin_amdgcn_mfma_f32_16x16x32_bf16(af, bf, oacc, 0, 0, 0);
        }
        const int row = (l >> 4) * 4;        // t_local base
        const int col = w * 16 + (l & 15);   // d
        float* mp = merged + ((size_t)(b * 512 + t0 + row)) * 512 + h * 64 + col;
        #pragma unroll
        for (int r = 0; r < 4; ++r) mp[r * 512] = oacc[r];
    }
}

// ======= output projection (split-bf16 MFMA) v2: C = A@Wo + bo =======
// 32x32 tiles, K split across wave-pairs (waves 0-3: k<256, 4-7: k>=256)
// -> grid (16,32) = 512 blocks (2 blocks/CU, 4 waves/SIMD), 4 K-iters.
// LDS cross-wave reduction combines the two K-halves (fp32 reassoc only).
__global__ __launch_bounds__(512) void gemm_out_mfma(
    const float* __restrict__ A, const float* __restrict__ W,
    const float* __restrict__ bias, float* __restrict__ C)
{
    __shared__ __align__(16) short BUF[256 * 72];   // 36864 B
    short (*Ah0)[72] = (short(*)[72])BUF;
    short (*Al0)[72] = (short(*)[72])(BUF + 32 * 72);
    short (*Ah1)[72] = (short(*)[72])(BUF + 64 * 72);
    short (*Al1)[72] = (short(*)[72])(BUF + 96 * 72);
    short (*Wh0)[72] = (short(*)[72])(BUF + 128 * 72);
    short (*Wl0)[72] = (short(*)[72])(BUF + 160 * 72);
    short (*Wh1)[72] = (short(*)[72])(BUF + 192 * 72);
    short (*Wl1)[72] = (short(*)[72])(BUF + 224 * 72);
    float (*Sred)[16][17] = (float(*)[16][17])BUF;  // 4 slots, 4352 B (aliased)

    const int tid = threadIdx.x;
    const int n0 = blockIdx.x * 32;
    const int m0 = blockIdx.y * 32;
    const int wv = tid >> 6;
    const int l  = tid & 63;
    const int kh = wv >> 2;             // K-half 0/1
    const int slot = wv & 3;            // (m-strip, n-strip) slot
    const int ms = (slot & 1) * 16;
    const int ns16 = (slot >> 1) * 16;
    const int fr = l & 15;
    const int fq = l >> 4;

    // staging indices: A two 32x64 tiles (one per K-half), W two 64x32 tiles
    const int arow = tid >> 4;          // 0..31
    const int acol = (tid & 15) * 4;    // 0..60
    const int wn   = tid & 31;          // 0..31 (n)
    const int wkr  = (tid >> 5) * 4;    // k base 0..60

    floatx4 acc = {0.f, 0.f, 0.f, 0.f};

    float4 a0 = *(const float4*)&A[(m0 + arow) * 512 + acol];
    float4 a1 = *(const float4*)&A[(m0 + arow) * 512 + 256 + acol];
    float wr0[4], wr1[4];
    #pragma unroll
    for (int i = 0; i < 4; ++i) {
        wr0[i] = W[(wkr + i) * 512 + n0 + wn];
        wr1[i] = W[(256 + wkr + i) * 512 + n0 + wn];
    }

    for (int k0 = 0; k0 < 256; k0 += 64) {
        __syncthreads();
        {
            bshort4 h4, l4;
            split4(a0, h4, l4);
            *(bshort4*)&Ah0[arow][acol] = h4;
            *(bshort4*)&Al0[arow][acol] = l4;
            split4(a1, h4, l4);
            *(bshort4*)&Ah1[arow][acol] = h4;
            *(bshort4*)&Al1[arow][acol] = l4;
            union { bshort4 v; short s[4]; } WH, WL;
            #pragma unroll
            for (int i = 0; i < 4; ++i) {
                short hh = bfh(wr0[i]);
                WH.s[i] = hh;
                WL.s[i] = bfh(wr0[i] - bff(hh));
            }
            *(bshort4*)&Wh0[wn][wkr] = WH.v;
            *(bshort4*)&Wl0[wn][wkr] = WL.v;
            #pragma unroll
            for (int i = 0; i < 4; ++i) {
                short hh = bfh(wr1[i]);
                WH.s[i] = hh;
                WL.s[i] = bfh(wr1[i] - bff(hh));
            }
            *(bshort4*)&Wh1[wn][wkr] = WH.v;
            *(bshort4*)&Wl1[wn][wkr] = WL.v;
        }
        __syncthreads();
        if (k0 + 64 < 256) {
            a0 = *(const float4*)&A[(m0 + arow) * 512 + k0 + 64 + acol];
            a1 = *(const float4*)&A[(m0 + arow) * 512 + 256 + k0 + 64 + acol];
            #pragma unroll
            for (int i = 0; i < 4; ++i) {
                wr0[i] = W[(k0 + 64 + wkr + i) * 512 + n0 + wn];
                wr1[i] = W[(256 + k0 + 64 + wkr + i) * 512 + n0 + wn];
            }
        }
        const short (*AhP)[72] = kh ? Ah1 : Ah0;
        const short (*AlP)[72] = kh ? Al1 : Al0;
        const short (*WhP)[72] = kh ? Wh1 : Wh0;
        const short (*WlP)[72] = kh ? Wl1 : Wl0;
        #pragma unroll
        for (int kc = 0; kc < 2; ++kc) {
            const int ko = kc * 32 + fq * 8;
            short8 ah = *(const short8*)&AhP[ms + fr][ko];
            short8 al = *(const short8*)&AlP[ms + fr][ko];
            short8 wh = *(const short8*)&WhP[ns16 + fr][ko];
            short8 wl = *(const short8*)&WlP[ns16 + fr][ko];
            acc = __builtin_amdgcn_mfma_f32_16x16x32_bf16(ah, wh, acc, 0, 0, 0);
            acc = __builtin_amdgcn_mfma_f32_16x16x32_bf16(ah, wl, acc, 0, 0, 0);
            acc = __builtin_amdgcn_mfma_f32_16x16x32_bf16(al, wh, acc, 0, 0, 0);
        }
    }

    // combine K-halves: kh=1 waves park in LDS, kh=0 waves add + store
    __syncthreads();
    if (kh == 1) {
        #pragma unroll
        for (int r = 0; r < 4; ++r) Sred[slot][fq * 4 + r][fr] = acc[r];
    }
    __syncthreads();
    if (kh == 0) {
        const float bb = bias[n0 + ns16 + fr];
        const int mrow = m0 + ms + fq * 4;
        const int ncol = n0 + ns16 + fr;
        #pragma unroll
        for (int r = 0; r < 4; ++r)
            C[(size_t)(mrow + r) * 512 + ncol] = acc[r] + Sred[slot][fq * 4 + r][fr] + bb;
    }
}

extern "C" void kernel_launch(void* const* d_in, const int* in_sizes, int n_in,
                              void* d_out, int out_size, void* d_ws, size_t ws_size,
                              hipStream_t stream) {
    (void)in_sizes; (void)n_in; (void)out_size; (void)ws_size;
    const float* query = (const float*)d_in[0];
    const float* key   = (const float*)d_in[1];
    // d_in[2] (value), d_in[7] (Wv), d_in[8] (bv): dead in the reference
    const float* Wq   = (const float*)d_in[3];
    const float* bq   = (const float*)d_in[4];
    const float* Wk   = (const float*)d_in[5];
    const float* bk   = (const float*)d_in[6];
    const float* Wq_h = (const float*)d_in[9];
    const float* Wk_h = (const float*)d_in[10];
    const float* va_h = (const float*)d_in[11];
    const float* b_h  = (const float*)d_in[12];
    const float* Wo   = (const float*)d_in[13];
    const float* bo   = (const float*)d_in[14];

    float* out = (float*)d_out;
    float* ws = (float*)d_ws;
    const int SZ = 1024 * 512;        // 524288 floats
    float* eqb     = ws;
    float* ekTb    = eqb + SZ;
    float* mergedb = ekTb + SZ;
    __hip_bfloat16* KhTb = (__hip_bfloat16*)(mergedb + SZ);   // 524288 bf16

    // fused: {Q,K} = In@W+b (split-bf16 MFMA), per-head transform -> eq/ekT/KhT
    // 512 blocks (2/CU) for barrier/latency overlap across co-resident blocks
    qk_head_mfma<<<dim3(8, 32, 2), 512, 0, stream>>>(query, key, Wq, bq, Wk, bk,
                                                     Wq_h, Wk_h, b_h,
                                                     eqb, ekTb, KhTb);
    // scores (4-way rational) -> softmax -> P@K (MFMA); 512 blocks, XCD-swizzled
    attn_v7<<<dim3(512, 1, 1), 512, 0, stream>>>(eqb, ekTb, KhTb, va_h, mergedb);
    // out = merged@Wo + bo (split-bf16 MFMA, K-split, 512 blocks)
    gemm_out_mfma<<<dim3(16, 32, 1), 512, 0, stream>>>(mergedb, Wo, bo, out);
}

// Round 11
// 157.610 us; speedup vs baseline: 1.1172x; 1.0073x over previous
//
#include <hip/hip_runtime.h>
#include <hip/hip_bf16.h>

#define T_SEQ 512
#define NH 8
#define DEPTH 64
#define UNITS_ 512
#define SCALE2 2.8853900817779268f   // 2*log2(e)
#define LOG2E 1.4426950408889634f

typedef __attribute__((ext_vector_type(4))) short bshort4;
typedef __attribute__((ext_vector_type(8))) short short8;
typedef __attribute__((ext_vector_type(4))) float floatx4;

// ---- bf16 helpers: split fp32 x = hi + lo (both bf16-representable) ----
static __device__ __forceinline__ short bfh(float x) {
    __hip_bfloat16 b(x);
    return *(short*)&b;
}
static __device__ __forceinline__ float bff(short s) {
    unsigned u = ((unsigned)(unsigned short)s) << 16;
    float f;
    __builtin_memcpy(&f, &u, 4);
    return f;
}
static __device__ __forceinline__ void split4(float4 x, bshort4& h, bshort4& l) {
    union { bshort4 v; short s[4]; } H, L;
    float xs[4] = {x.x, x.y, x.z, x.w};
    #pragma unroll
    for (int i = 0; i < 4; ++i) {
        short hh = bfh(xs[i]);
        H.s[i] = hh;
        L.s[i] = bfh(xs[i] - bff(hh));
    }
    h = H.v; l = L.v;
}

// ======= fused QK projection (split-bf16 MFMA) + per-head transform =======
// 32-row m-tiles -> grid (8,32,2) = 512 blocks.
// __launch_bounds__(512, 4): min 4 waves/SIMD -> VGPR cap 128 -> TWO blocks
// co-resident per CU (plain (512) allowed up to 256 VGPR = 1 block/CU, which
// left every barrier + MFMA dep-chain exposed; R8's grid-doubling was null
// because a second block couldn't fit).
__global__ __launch_bounds__(512, 4) void qk_head_mfma(
    const float* __restrict__ query, const float* __restrict__ key,
    const float* __restrict__ Wq, const float* __restrict__ bq,
    const float* __restrict__ Wk, const float* __restrict__ bk,
    const float* __restrict__ Wq_h, const float* __restrict__ Wk_h,
    const float* __restrict__ bh,
    float* __restrict__ eq, float* __restrict__ ekT,
    __hip_bfloat16* __restrict__ KhT)
{
    // stage1: Ah/Al bf16[32][72], Wh/Wl bf16[64][72]  (27648 B)
    // stage2 (aliased): S1 = C^T fp32[64][36] (9216 B), S2 fp32[64][68] (17408 B)
    __shared__ __align__(16) short BUF[192 * 72];
    short (*Ah)[72] = (short(*)[72])BUF;
    short (*Al)[72] = (short(*)[72])(BUF + 32 * 72);
    short (*Wh)[72] = (short(*)[72])(BUF + 64 * 72);
    short (*Wl)[72] = (short(*)[72])(BUF + 128 * 72);
    float (*S1)[36] = (float(*)[36])BUF;                 // C^T [n64][m32]
    float (*S2)[68] = (float(*)[68])(BUF + 4608);        // byte offset 9216

    const int tid = threadIdx.x;
    const int which = blockIdx.z;            // 0 = Q path, 1 = K path
    const int h  = blockIdx.x;
    const int m0 = blockIdx.y * 32;          // row in [0,1024): b*512 + t
    const int n0 = h * 64;
    const int b  = m0 >> 9;
    const int t0 = m0 & 511;
    const int bh_i = b * NH + h;

    const float* In   = which ? key : query;
    const float* W    = which ? Wk  : Wq;
    const float* bias = which ? bk  : bq;
    const float* Wp   = (which ? Wk_h : Wq_h) + h * 4096;

    const int wv = tid >> 6;            // wave 0..7
    const int l  = tid & 63;
    const int ms = (wv & 1) * 16;       // m-strip
    const int ns16 = (wv >> 1) * 16;    // n-tile (4 tiles of 16)
    const int fr = l & 15;              // fragment row/col index
    const int fq = l >> 4;              // k-slice quarter

    // staging indices
    const int arow = tid >> 4;          // 0..31
    const int acol = (tid & 15) * 4;    // 0..60
    const int wn   = tid & 63;          // W: n 0..63 (lane-coalesced)
    const int wkb  = (tid >> 6) * 8;    // W: k base 0..56

    // per-head weight tile prefetch (held in regs through stage 1)
    const int hwrow = tid >> 3;         // d 0..63
    const int hwcol = (tid & 7) * 8;    // e base
    float4 whA = *(const float4*)&Wp[hwrow * 64 + hwcol];
    float4 whB = *(const float4*)&Wp[hwrow * 64 + hwcol + 4];

    const float bbn = bias[n0 + ns16 + fr];

    floatx4 acc = {0.f, 0.f, 0.f, 0.f};

    // prefetch k-tile 0
    float4 a0 = *(const float4*)&In[(m0 + arow) * 512 + acol];
    float wr[8];
    #pragma unroll
    for (int i = 0; i < 8; ++i) wr[i] = W[(wkb + i) * 512 + n0 + wn];

    for (int k0 = 0; k0 < 512; k0 += 64) {
        __syncthreads();
        {   // convert + stage
            bshort4 h4, l4;
            split4(a0, h4, l4);
            *(bshort4*)&Ah[arow][acol] = h4;
            *(bshort4*)&Al[arow][acol] = l4;
            union { short8 v; short s[8]; } WH, WL;
            #pragma unroll
            for (int i = 0; i < 8; ++i) {
                short hh = bfh(wr[i]);
                WH.s[i] = hh;
                WL.s[i] = bfh(wr[i] - bff(hh));
            }
            *(short8*)&Wh[wn][wkb] = WH.v;
            *(short8*)&Wl[wn][wkb] = WL.v;
        }
        __syncthreads();
        if (k0 + 64 < 512) {            // prefetch next k-tile under the MFMAs
            a0 = *(const float4*)&In[(m0 + arow) * 512 + k0 + 64 + acol];
            #pragma unroll
            for (int i = 0; i < 8; ++i)
                wr[i] = W[(k0 + 64 + wkb + i) * 512 + n0 + wn];
        }
        #pragma unroll
        for (int kc = 0; kc < 2; ++kc) {
            const int ko = kc * 32 + fq * 8;
            short8 ah = *(const short8*)&Ah[ms + fr][ko];
            short8 al = *(const short8*)&Al[ms + fr][ko];
            short8 wh = *(const short8*)&Wh[ns16 + fr][ko];
            short8 wl = *(const short8*)&Wl[ns16 + fr][ko];
            acc = __builtin_amdgcn_mfma_f32_16x16x32_bf16(ah, wh, acc, 0, 0, 0);
            acc = __builtin_amdgcn_mfma_f32_16x16x32_bf16(ah, wl, acc, 0, 0, 0);
            acc = __builtin_amdgcn_mfma_f32_16x16x32_bf16(al, wh, acc, 0, 0, 0);
        }
    }

    // ---- stage 2: per-head 32x64 @ 64x64 transform (fp32 VALU) ----
    __syncthreads();   // all MFMA LDS reads done; BUF repurposed
    #pragma unroll
    for (int r = 0; r < 4; ++r)
        S1[ns16 + fr][ms + fq * 4 + r] = acc[r] + bbn;    // C^T [n][m]
    *(float4*)&S2[hwrow][hwcol]     = whA;                // Wh_head [d][e]
    *(float4*)&S2[hwrow][hwcol + 4] = whB;
    __syncthreads();

    const int ti = tid >> 4;            // row t 0..31 (16-lane groups share row)
    const int tj = tid & 15;            // cols 4tj..4tj+3
    float4 qa = make_float4(0.f, 0.f, 0.f, 0.f);
    #pragma unroll 16
    for (int d = 0; d < 64; ++d) {
        float a = S1[d][ti];            // broadcast within 16-lane group
        float4 b4 = *(const float4*)&S2[d][4 * tj];
        qa.x = fmaf(a, b4.x, qa.x);
        qa.y = fmaf(a, b4.y, qa.y);
        qa.z = fmaf(a, b4.z, qa.z);
        qa.w = fmaf(a, b4.w, qa.w);
    }

    if (which == 0) {
        float* outp = eq + ((size_t)bh_i * 512 + t0 + ti) * 64 + 4 * tj;
        float4 o;
        o.x = __builtin_amdgcn_exp2f(SCALE2 * qa.x);
        o.y = __builtin_amdgcn_exp2f(SCALE2 * qa.y);
        o.z = __builtin_amdgcn_exp2f(SCALE2 * qa.z);
        o.w = __builtin_amdgcn_exp2f(SCALE2 * qa.w);
        *(float4*)outp = o;
        return;
    }

    // which == 1: ekT (transposed, exp2'd, +b_h) and KhT (bf16 of C^T)
    float4 bhv = *(const float4*)&bh[h * 64 + 4 * tj];
    __syncthreads();   // all threads done reading S2 as per-head weights
    S2[4 * tj + 0][ti] = __builtin_amdgcn_exp2f(SCALE2 * (qa.x + bhv.x));
    S2[4 * tj + 1][ti] = __builtin_amdgcn_exp2f(SCALE2 * (qa.y + bhv.y));
    S2[4 * tj + 2][ti] = __builtin_amdgcn_exp2f(SCALE2 * (qa.z + bhv.z));
    S2[4 * tj + 3][ti] = __builtin_amdgcn_exp2f(SCALE2 * (qa.w + bhv.w));
    __syncthreads();

    const int dd = tid >> 3;            // e (or d) 0..63
    const int sc = (tid & 7) * 4;       // s chunk 0..28
    float* ekp = ekT + ((size_t)bh_i * 64 + dd) * 512 + t0 + sc;
    *(float4*)ekp = *(float4*)&S2[dd][sc];

    __hip_bfloat16* kp = KhT + ((size_t)bh_i * 64 + dd) * 512 + t0 + sc;
    union { bshort4 v; short s[4]; } pk;
    #pragma unroll
    for (int i = 0; i < 4; ++i) pk.s[i] = bfh(S1[dd][sc + i]);
    *(bshort4*)kp = pk.v;
}

// ============ additive-attention core v7 (VERBATIM, verified 58 us) ============
__global__ __launch_bounds__(512, 4) void attn_v7(
    const float* __restrict__ eq, const float* __restrict__ ekT,
    const __hip_bfloat16* __restrict__ KhT, const float* __restrict__ va_h,
    float* __restrict__ merged)
{
    __shared__ __hip_bfloat16 pA[16][520];   // p in MFMA-A layout source, bf16
    __shared__ float wsum[16][8];

    const int tid = threadIdx.x;
    const int w = tid >> 6;
    const int l = tid & 63;
    const int bid = blockIdx.x;
    const int swz = (bid & 7) * 64 + (bid >> 3);   // bijective: 512 % 8 == 0
    const int t0 = (swz & 31) * 16;
    const int bh_i = swz >> 5;          // 0..15 = b*8 + h
    const int h = bh_i & 7;
    const int b = bh_i >> 3;

    const float* eq_p = eq + ((size_t)bh_i * 512 + t0) * 64;
    const float* ekT_p = ekT + (size_t)bh_i * 64 * 512 + tid;   // this thread's s
    const float* va_p = va_h + h * 64;

    float acc[16];
    #pragma unroll
    for (int t = 0; t < 16; ++t) acc[t] = 0.f;

    // process e in 4 chunks of 16, double-buffered in NAMED arrays (rule #20)
    float ekA[16], ekB[16];
    #pragma unroll
    for (int j = 0; j < 16; ++j) ekA[j] = ekT_p[j * 512];

#define SCORE_CHUNK(EKREG, E0)                                                  \
    {                                                                           \
        _Pragma("unroll")                                                       \
        for (int t = 0; t < 16; ++t) {                                          \
            float a = acc[t];                                                   \
            _Pragma("unroll")                                                   \
            for (int g = 0; g < 4; ++g) {                                       \
                float4 q4 = *(const float4*)&eq_p[t * 64 + (E0) + g * 4];       \
                float4 v4 = *(const float4*)&va_p[(E0) + g * 4];                \
                float u0 = fmaf(q4.x, EKREG[g * 4 + 0], 1.0f);                  \
                float u1 = fmaf(q4.y, EKREG[g * 4 + 1], 1.0f);                  \
                float u2 = fmaf(q4.z, EKREG[g * 4 + 2], 1.0f);                  \
                float u3 = fmaf(q4.w, EKREG[g * 4 + 3], 1.0f);                  \
                float d01 = u0 * u1;                                            \
                float n01 = fmaf(v4.x, u1, v4.y * u0);                          \
                float d23 = u2 * u3;                                            \
                float n23 = fmaf(v4.z, u3, v4.w * u2);                          \
                float D = d01 * d23;                                            \
                float N = fmaf(n01, d23, n23 * d01);                            \
                a = fmaf(N, __builtin_amdgcn_rcpf(D), a);                       \
            }                                                                   \
            acc[t] = a;                                                         \
        }                                                                       \
    }

    #pragma unroll
    for (int j = 0; j < 16; ++j) ekB[j] = ekT_p[(16 + j) * 512];
    SCORE_CHUNK(ekA, 0)
    #pragma unroll
    for (int j = 0; j < 16; ++j) ekA[j] = ekT_p[(32 + j) * 512];
    SCORE_CHUNK(ekB, 16)
    #pragma unroll
    for (int j = 0; j < 16; ++j) ekB[j] = ekT_p[(48 + j) * 512];
    SCORE_CHUNK(ekA, 32)
    SCORE_CHUNK(ekB, 48)
#undef SCORE_CHUNK

    // exp (no max-subtract; |score| bounded ~5) + per-t sum across 512 threads
    float ev[16];
    #pragma unroll
    for (int t = 0; t < 16; ++t) {
        float s = __builtin_amdgcn_exp2f(-SCALE2 * acc[t]);   // exp(-2*S_t)
        ev[t] = s;
        #pragma unroll
        for (int off = 32; off > 0; off >>= 1) s += __shfl_xor(s, off, 64);
        if (l == 0) wsum[t][w] = s;
    }
    __syncthreads();
    #pragma unroll
    for (int t = 0; t < 16; ++t) {
        float4 s0 = *(float4*)&wsum[t][0];
        float4 s1 = *(float4*)&wsum[t][4];
        float inv = 1.0f / (((s0.x + s0.y) + (s0.z + s0.w)) + ((s1.x + s1.y) + (s1.z + s1.w)));
        pA[t][tid] = __hip_bfloat16(ev[t] * inv);   // normalized p, bf16
    }
    __syncthreads();

    // P (16x512) @ K (512x64): 4 waves, wave w owns d-range [16w,16w+16)
    if (w < 4) {
        const __hip_bfloat16* kp = KhT + (size_t)bh_i * 64 * 512
                                   + ((size_t)(w * 16 + (l & 15))) * 512 + (l >> 4) * 8;
        const __hip_bfloat16* ap = &pA[l & 15][(l >> 4) * 8];
        floatx4 oacc = {0.f, 0.f, 0.f, 0.f};
        #pragma unroll
        for (int kt = 0; kt < 16; ++kt) {
            short8 af = *(const short8*)(ap + kt * 32);
            short8 bf = *(const short8*)(kp + kt * 32);
            oacc = __builtin_amdgcn_mfma_f32_16x16x32_bf16(af, bf, oacc, 0, 0, 0);
        }
        const int row = (l >> 4) * 4;        // t_local base
        const int col = w * 16 + (l & 15);   // d
        float* mp = merged + ((size_t)(b * 512 + t0 + row)) * 512 + h * 64 + col;
        #pragma unroll
        for (int r = 0; r < 4; ++r) mp[r * 512] = oacc[r];
    }
}

// ======= output projection (split-bf16 MFMA): C = A@Wo + bo =======
// 32x32 tiles, K split across wave-pairs -> grid (16,32) = 512 blocks.
// __launch_bounds__(512, 4): VGPR cap 128 -> 2 blocks/CU (see qk comment).
__global__ __launch_bounds__(512, 4) void gemm_out_mfma(
    const float* __restrict__ A, const float* __restrict__ W,
    const float* __restrict__ bias, float* __restrict__ C)
{
    __shared__ __align__(16) short BUF[256 * 72];   // 36864 B
    short (*Ah0)[72] = (short(*)[72])BUF;
    short (*Al0)[72] = (short(*)[72])(BUF + 32 * 72);
    short (*Ah1)[72] = (short(*)[72])(BUF + 64 * 72);
    short (*Al1)[72] = (short(*)[72])(BUF + 96 * 72);
    short (*Wh0)[72] = (short(*)[72])(BUF + 128 * 72);
    short (*Wl0)[72] = (short(*)[72])(BUF + 160 * 72);
    short (*Wh1)[72] = (short(*)[72])(BUF + 192 * 72);
    short (*Wl1)[72] = (short(*)[72])(BUF + 224 * 72);
    float (*Sred)[16][17] = (float(*)[16][17])BUF;  // 4 slots, 4352 B (aliased)

    const int tid = threadIdx.x;
    const int n0 = blockIdx.x * 32;
    const int m0 = blockIdx.y * 32;
    const int wv = tid >> 6;
    const int l  = tid & 63;
    const int kh = wv >> 2;             // K-half 0/1
    const int slot = wv & 3;            // (m-strip, n-strip) slot
    const int ms = (slot & 1) * 16;
    const int ns16 = (slot >> 1) * 16;
    const int fr = l & 15;
    const int fq = l >> 4;

    // staging indices: A two 32x64 tiles (one per K-half), W two 64x32 tiles
    const int arow = tid >> 4;          // 0..31
    const int acol = (tid & 15) * 4;    // 0..60
    const int wn   = tid & 31;          // 0..31 (n)
    const int wkr  = (tid >> 5) * 4;    // k base 0..60

    floatx4 acc = {0.f, 0.f, 0.f, 0.f};

    float4 a0 = *(const float4*)&A[(m0 + arow) * 512 + acol];
    float4 a1 = *(const float4*)&A[(m0 + arow) * 512 + 256 + acol];
    float wr0[4], wr1[4];
    #pragma unroll
    for (int i = 0; i < 4; ++i) {
        wr0[i] = W[(wkr + i) * 512 + n0 + wn];
        wr1[i] = W[(256 + wkr + i) * 512 + n0 + wn];
    }

    for (int k0 = 0; k0 < 256; k0 += 64) {
        __syncthreads();
        {
            bshort4 h4, l4;
            split4(a0, h4, l4);
            *(bshort4*)&Ah0[arow][acol] = h4;
            *(bshort4*)&Al0[arow][acol] = l4;
            split4(a1, h4, l4);
            *(bshort4*)&Ah1[arow][acol] = h4;
            *(bshort4*)&Al1[arow][acol] = l4;
            union { bshort4 v; short s[4]; } WH, WL;
            #pragma unroll
            for (int i = 0; i < 4; ++i) {
                short hh = bfh(wr0[i]);
                WH.s[i] = hh;
                WL.s[i] = bfh(wr0[i] - bff(hh));
            }
            *(bshort4*)&Wh0[wn][wkr] = WH.v;
            *(bshort4*)&Wl0[wn][wkr] = WL.v;
            #pragma unroll
            for (int i = 0; i < 4; ++i) {
                short hh = bfh(wr1[i]);
                WH.s[i] = hh;
                WL.s[i] = bfh(wr1[i] - bff(hh));
            }
            *(bshort4*)&Wh1[wn][wkr] = WH.v;
            *(bshort4*)&Wl1[wn][wkr] = WL.v;
        }
        __syncthreads();
        if (k0 + 64 < 256) {
            a0 = *(const float4*)&A[(m0 + arow) * 512 + k0 + 64 + acol];
            a1 = *(const float4*)&A[(m0 + arow) * 512 + 256 + k0 + 64 + acol];
            #pragma unroll
            for (int i = 0; i < 4; ++i) {
                wr0[i] = W[(k0 + 64 + wkr + i) * 512 + n0 + wn];
                wr1[i] = W[(256 + k0 + 64 + wkr + i) * 512 + n0 + wn];
            }
        }
        const short (*AhP)[72] = kh ? Ah1 : Ah0;
        const short (*AlP)[72] = kh ? Al1 : Al0;
        const short (*WhP)[72] = kh ? Wh1 : Wh0;
        const short (*WlP)[72] = kh ? Wl1 : Wl0;
        #pragma unroll
        for (int kc = 0; kc < 2; ++kc) {
            const int ko = kc * 32 + fq * 8;
            short8 ah = *(const short8*)&AhP[ms + fr][ko];
            short8 al = *(const short8*)&AlP[ms + fr][ko];
            short8 wh = *(const short8*)&WhP[ns16 + fr][ko];
            short8 wl = *(const short8*)&WlP[ns16 + fr][ko];
            acc = __builtin_amdgcn_mfma_f32_16x16x32_bf16(ah, wh, acc, 0, 0, 0);
            acc = __builtin_amdgcn_mfma_f32_16x16x32_bf16(ah, wl, acc, 0, 0, 0);
            acc = __builtin_amdgcn_mfma_f32_16x16x32_bf16(al, wh, acc, 0, 0, 0);
        }
    }

    // combine K-halves: kh=1 waves park in LDS, kh=0 waves add + store
    __syncthreads();
    if (kh == 1) {
        #pragma unroll
        for (int r = 0; r < 4; ++r) Sred[slot][fq * 4 + r][fr] = acc[r];
    }
    __syncthreads();
    if (kh == 0) {
        const float bb = bias[n0 + ns16 + fr];
        const int mrow = m0 + ms + fq * 4;
        const int ncol = n0 + ns16 + fr;
        #pragma unroll
        for (int r = 0; r < 4; ++r)
            C[(size_t)(mrow + r) * 512 + ncol] = acc[r] + Sred[slot][fq * 4 + r][fr] + bb;
    }
}

extern "C" void kernel_launch(void* const* d_in, const int* in_sizes, int n_in,
                              void* d_out, int out_size, void* d_ws, size_t ws_size,
                              hipStream_t stream) {
    (void)in_sizes; (void)n_in; (void)out_size; (void)ws_size;
    const float* query = (const float*)d_in[0];
    const float* key   = (const float*)d_in[1];
    // d_in[2] (value), d_in[7] (Wv), d_in[8] (bv): dead in the reference
    const float* Wq   = (const float*)d_in[3];
    const float* bq   = (const float*)d_in[4];
    const float* Wk   = (const float*)d_in[5];
    const float* bk   = (const float*)d_in[6];
    const float* Wq_h = (const float*)d_in[9];
    const float* Wk_h = (const float*)d_in[10];
    const float* va_h = (const float*)d_in[11];
    const float* b_h  = (const float*)d_in[12];
    const float* Wo   = (const float*)d_in[13];
    const float* bo   = (const float*)d_in[14];

    float* out = (float*)d_out;
    float* ws = (float*)d_ws;
    const int SZ = 1024 * 512;        // 524288 floats
    float* eqb     = ws;
    float* ekTb    = eqb + SZ;
    float* mergedb = ekTb + SZ;
    __hip_bfloat16* KhTb = (__hip_bfloat16*)(mergedb + SZ);   // 524288 bf16

    // fused: {Q,K} = In@W+b (split-bf16 MFMA), per-head transform -> eq/ekT/KhT
    qk_head_mfma<<<dim3(8, 32, 2), 512, 0, stream>>>(query, key, Wq, bq, Wk, bk,
                                                     Wq_h, Wk_h, b_h,
                                                     eqb, ekTb, KhTb);
    // scores (4-way rational) -> softmax -> P@K (MFMA); 512 blocks, XCD-swizzled
    attn_v7<<<dim3(512, 1, 1), 512, 0, stream>>>(eqb, ekTb, KhTb, va_h, mergedb);
    // out = merged@Wo + bo (split-bf16 MFMA, K-split, 512 blocks)
    gemm_out_mfma<<<dim3(16, 32, 1), 512, 0, stream>>>(mergedb, Wo, bo, out);
}